// Round 2
// 212.234 us; speedup vs baseline: 1.1735x; 1.1735x over previous
//
#include <hip/hip_runtime.h>
#include <math.h>

typedef unsigned int u32;
typedef unsigned short u16;
typedef unsigned long long u64;

#define PRE_NMS 6000
#define NBLK    94          /* ceil(6000/64) rank-bitmap words */
#define KMAX    640         /* group capacity (E[K]~375) */
#define MSTRIDE 11          /* maskm row stride, > KMAX/64 */
#define FINEB   8192        /* [0.5,1) buckets, 2^10 ulp each */
#define LOWB    8064        /* [0,0.5) buckets, bits>>17 */
#define TOTB    (FINEB + LOWB)
#define NHB     16          /* hist partial copies */
#define CANDMAX 16384
#define SLICES  8
#define NGRP    24
#define FLOOR_BITS 0x3F000000u   /* 0.5f */

/* ws byte offsets */
#define CTR_OFF   0          /* 64 u32: [0]=cand count [1]=pivot bits */
#define RANKS_OFF 256        /* 16384 u32 -> 65792 */
#define PART_OFF  65792      /* 16 x 16256 u32 -> 1106176 */
#define CAND_OFF  1106176    /* 16384 u64 -> 1237248 */
#define BOXR_OFF  1237248    /* 6016 float4 -> 1333504 */
#define GBITS_OFF 1333504    /* 24*192 u32 -> 1351936 */

/* 1: dual-range partial histograms; full-range exact, fine resolution on top */
__global__ __launch_bounds__(1024) void hist_kernel(const float4* __restrict__ probs4,
                                                    u32* __restrict__ partials, int n_prop) {
    __shared__ u32 hf[FINEB];      /* 32 KB, 1 copy (sparse traffic) */
    __shared__ u32 hl[2][LOWB];    /* 63 KB, 2 copies (bulk traffic) */
    int t = threadIdx.x;
    for (int i = t; i < FINEB; i += 1024) hf[i] = 0u;
    for (int i = t; i < 2 * LOWB; i += 1024) ((u32*)hl)[i] = 0u;
    __syncthreads();
    u32* l = hl[(t >> 6) & 1];
    int nq = n_prop >> 2;                     /* 4 props per iter */
    int idx = blockIdx.x * 1024 + t;
    int stride = gridDim.x * 1024;
    for (int q = idx; q < nq; q += stride) {
        float4 a = probs4[3 * q + 0];
        float4 b = probs4[3 * q + 1];
        float4 c = probs4[3 * q + 2];
        float vs[8] = {a.y, a.z, b.x, b.y, b.w, c.x, c.z, c.w};
        #pragma unroll
        for (int e = 0; e < 8; ++e) {
            u32 bits = __float_as_uint(vs[e]);
            if (bits >= FLOOR_BITS) {
                u32 fb = (bits - FLOOR_BITS) >> 10; if (fb >= FINEB) fb = FINEB - 1;
                atomicAdd(&hf[fb], 1u);
            } else {
                atomicAdd(&l[bits >> 17], 1u);
            }
        }
    }
    __syncthreads();
    u32* outp = partials + blockIdx.x * TOTB;
    for (int b = t; b < FINEB; b += 1024) outp[b] = hf[b];
    for (int b = t; b < LOWB; b += 1024) outp[FINEB + b] = hl[0][b] + hl[1][b];
}

/* 2: reduce partials, suffix-scan from top -> exact pivot; zero ctr/ranks/gbits */
__global__ __launch_bounds__(1024) void pivot_kernel(const u32* __restrict__ partials,
                                                     u32* __restrict__ ctr,
                                                     u32* __restrict__ ranks,
                                                     u32* __restrict__ gbits) {
    __shared__ u32 fh[FINEB];
    __shared__ u32 sd[1024];
    int t = threadIdx.x;
    for (int i = t; i < CANDMAX; i += 1024) ranks[i] = 0u;
    for (int i = t; i < NGRP * 192; i += 1024) gbits[i] = 0u;
    if (t == 0) ctr[0] = 0u;
    for (int b = t; b < FINEB; b += 1024) {
        u32 s = 0;
        #pragma unroll
        for (int k = 0; k < NHB; ++k) s += partials[k * TOTB + b];
        fh[b] = s;
    }
    __syncthreads();
    int hi = FINEB - 1 - 8 * t;
    u32 L = 0;
    #pragma unroll
    for (int e = 0; e < 8; ++e) L += fh[hi - e];
    sd[t] = L;
    __syncthreads();
    for (int off = 1; off < 1024; off <<= 1) {
        u32 x = (t >= off) ? sd[t - off] : 0u;
        __syncthreads();
        sd[t] += x;
        __syncthreads();
    }
    u32 incl = sd[t], excl = incl - L;
    u32 fineTotal = sd[1023];
    if (excl < (u32)PRE_NMS && incl >= (u32)PRE_NMS) {
        u32 run = excl;
        #pragma unroll
        for (int e = 0; e < 8; ++e) {
            u32 c = fh[hi - e];
            if (run < (u32)PRE_NMS && run + c >= (u32)PRE_NMS)
                ctr[1] = FLOOR_BITS + ((u32)(hi - e) << 10);
            run += c;
        }
    }
    if (fineTotal >= (u32)PRE_NMS) return;

    /* fallback (never expected): continue into [0, 0.5) coarse buckets */
    u32 rem = (u32)PRE_NMS - fineTotal;
    __syncthreads();
    for (int b = t; b < FINEB; b += 1024) {
        u32 s = 0;
        if (b < LOWB) {
            #pragma unroll
            for (int k = 0; k < NHB; ++k) s += partials[k * TOTB + FINEB + b];
        }
        fh[b] = s;
    }
    __syncthreads();
    L = 0;
    #pragma unroll
    for (int e = 0; e < 8; ++e) L += fh[hi - e];
    sd[t] = L;
    __syncthreads();
    for (int off = 1; off < 1024; off <<= 1) {
        u32 x = (t >= off) ? sd[t - off] : 0u;
        __syncthreads();
        sd[t] += x;
        __syncthreads();
    }
    incl = sd[t]; excl = incl - L;
    if (excl < rem && incl >= rem) {
        u32 run = excl;
        #pragma unroll
        for (int e = 0; e < 8; ++e) {
            u32 c = fh[hi - e];
            if (run < rem && run + c >= rem)
                ctr[1] = ((u32)(hi - e)) << 17;
            run += c;
        }
    }
}

/* 3: compact all candidates with bits >= pivot */
__global__ void compact_kernel(const float* __restrict__ probs, u32* ctr,
                               u64* __restrict__ cand, int nfg) {
    int i = blockIdx.x * blockDim.x + threadIdx.x;
    if (i >= nfg) return;
    u32 pivot = ctr[1];
    float v = probs[(i >> 1) * 3 + 1 + (i & 1)];
    u32 bits = __float_as_uint(v);
    if (bits >= pivot) {
        u32 pos = atomicAdd(&ctr[0], 1u);
        if (pos < (u32)CANDMAX) cand[pos] = ((u64)bits << 32) | (u64)(~(u32)i);
    }
}

/* 4: 2-D parallel rank-by-counting: grid (slice, keyblock); exact stable order */
__global__ __launch_bounds__(256) void rank_kernel(const u64* __restrict__ cand,
                                                   const u32* __restrict__ ctr,
                                                   u32* __restrict__ ranks) {
    __shared__ u64 tile[256];
    int t = threadIdx.x;
    u32 M = ctr[0]; if (M > (u32)CANDMAX) M = (u32)CANDMAX;
    int kb = blockIdx.y;
    if ((u32)(kb * 256) >= M) return;
    int i = kb * 256 + t;
    u64 key = (i < (int)M) ? cand[i] : 0ull;
    u32 Ls = (M + SLICES - 1) / SLICES;
    u32 s0 = blockIdx.x * Ls;
    u32 s1 = s0 + Ls; if (s1 > M) s1 = M;
    int cnt = 0;
    for (u32 base = s0; base < s1; base += 256) {
        u32 idx = base + t;
        tile[t] = (idx < s1) ? cand[idx] : 0ull;   /* 0-pad safe: real keys > 0 */
        __syncthreads();
        #pragma unroll 8
        for (int q = 0; q < 256; ++q) cnt += (tile[q] > key) ? 1 : 0;
        __syncthreads();
    }
    if (i < (int)M && cnt > 0) atomicAdd(&ranks[i], (u32)cnt);
}

/* 5: single-pass ROI decode + scatter. Full lane utilization, one decode per
   candidate (was 2x inside per-group blocks). Writes det rows, rank-indexed
   box table, and per-group rank bitmaps for the NMS kernel. */
__global__ __launch_bounds__(256) void decode_kernel(const u64* __restrict__ cand,
                                                     const u32* __restrict__ ranks,
                                                     const u32* __restrict__ ctr,
                                                     const float4* __restrict__ deltas4,
                                                     const float4* __restrict__ anchors4,
                                                     float4* __restrict__ boxr,
                                                     u32* __restrict__ gbits,
                                                     float* __restrict__ out,
                                                     int n_anch) {
    u32 i = blockIdx.x * 256 + threadIdx.x;
    u32 M = ctr[0]; if (M > (u32)CANDMAX) M = (u32)CANDMAX;
    if (i >= M) return;
    u32 r = ranks[i];
    if (r >= (u32)PRE_NMS) return;
    u64 key = cand[i];
    u32 bits = (u32)(key >> 32);
    u32 flat = ~((u32)key);
    int p = (int)(flat >> 1);
    int cls = (int)(flat & 1u) + 1;
    int b = p / n_anch;
    int g = b * 3 + cls;
    int aidx = p - b * n_anch;
    float score = __uint_as_float(bits);
    float4 a = anchors4[aidx];
    float4 d = deltas4[p];
    float d0 = d.x * 0.1f, d1 = d.y * 0.1f, d2 = d.z * 0.2f, d3 = d.w * 0.2f;
    float y1 = a.x * (1.0f / 512.0f), x1 = a.y * (1.0f / 512.0f);
    float y2 = a.z * (1.0f / 512.0f), x2 = a.w * (1.0f / 512.0f);
    float h = y2 - y1, w = x2 - x1;
    float cy = y1 + 0.5f * h + d0 * h;
    float cx = x1 + 0.5f * w + d1 * w;
    h = h * expf(d2);
    w = w * expf(d3);
    float ry1 = (cy - 0.5f * h) * 512.0f;
    float rx1 = (cx - 0.5f * w) * 512.0f;
    float ry2 = (cy - 0.5f * h + h) * 512.0f;
    float rx2 = (cx - 0.5f * w + w) * 512.0f;
    ry1 = fminf(fmaxf(ry1, 0.0f), 512.0f);
    rx1 = fminf(fmaxf(rx1, 0.0f), 512.0f);
    ry2 = fminf(fmaxf(ry2, 0.0f), 512.0f);
    rx2 = fminf(fmaxf(rx2, 0.0f), 512.0f);
    out[r * 6 + 0] = ry1;
    out[r * 6 + 1] = rx1;
    out[r * 6 + 2] = ry2;
    out[r * 6 + 3] = rx2;
    out[r * 6 + 4] = score;
    out[r * 6 + 5] = 1.0f;               /* default keep; nms overwrites */
    out[PRE_NMS * 6 + r] = (float)cls;
    out[PRE_NMS * 7 + r] = (float)b;
    boxr[r] = make_float4(ry1, rx1, ry2, rx2);
    atomicOr(&gbits[g * 192 + (r >> 5)], 1u << (r & 31));
}

/* 6: per-(batch,class) NMS. No re-decode: gather rank-ordered boxes from L2.
   Cross-group IoU never computed (separate blocks) => no group offset needed. */
__global__ __launch_bounds__(512) void nms_kernel(const u32* __restrict__ gbits,
                                                  const float4* __restrict__ boxr,
                                                  float* __restrict__ out) {
    __shared__ u64 maskm[KMAX * MSTRIDE + 64];   /* 56.8 KB */
    __shared__ float4 sbox[KMAX];                /* 10 KB */
    __shared__ float sarea[KMAX];
    __shared__ int bpre[96];
    __shared__ u16 grank[KMAX];                  /* pos -> rank */
    __shared__ int sK;
    int g = blockIdx.x, t = threadIdx.x, lane = t & 63, wv = t >> 6;
    const u32* rb32 = gbits + g * 192;

    /* A2: exclusive prefix over 94 bitmap words (wave 0) */
    if (t < 64) {
        u64 w0 = (u64)rb32[2 * lane] | ((u64)rb32[2 * lane + 1] << 32);
        u64 w1 = (lane < NBLK - 64)
                 ? ((u64)rb32[128 + 2 * lane] | ((u64)rb32[129 + 2 * lane] << 32)) : 0ull;
        int c0 = (int)__popcll(w0), c1 = (int)__popcll(w1);
        int i0 = c0, i1 = c1;
        #pragma unroll
        for (int off = 1; off < 64; off <<= 1) {
            int a = __shfl_up(i0, off); if (lane >= off) i0 += a;
            int b = __shfl_up(i1, off); if (lane >= off) i1 += b;
        }
        int tot0 = __shfl(i0, 63), tot1 = __shfl(i1, 63);
        bpre[lane] = i0 - c0;
        if (lane < 32) bpre[64 + lane] = tot0 + ((lane < NBLK - 64) ? (i1 - c1) : 0);
        if (lane == 0) sK = tot0 + tot1;
    }
    __syncthreads();
    int K = sK;
    if (K == 0) return;
    int Kc = (K < KMAX) ? K : KMAX;
    int W = (Kc + 63) >> 6;

    /* sentinel fill + maskm pre-zero (Phase B only writes upper-tri tiles) */
    for (int m = t; m < KMAX; m += 512) {
        sbox[m] = make_float4(-3e30f, -3e30f, -3e30f, -3e30f);
        sarea[m] = 3e38f;
    }
    for (int m = t; m < KMAX * MSTRIDE + 64; m += 512) maskm[m] = 0ull;
    __syncthreads();

    /* A3: scatter rank order -> grank */
    for (int blk = wv; blk < NBLK; blk += 8) {
        u64 wmask = (u64)rb32[2 * blk] | ((u64)rb32[2 * blk + 1] << 32);
        if ((wmask >> lane) & 1ull) {
            int pos = bpre[blk] + (int)__popcll(wmask & ((1ull << lane) - 1ull));
            if (pos < KMAX) grank[pos] = (u16)((blk << 6) | lane);
        }
    }
    __syncthreads();

    /* stage SoA in rank order from L2-hot box table (no decode) */
    for (int m = t; m < Kc; m += 512) {
        float4 bb = boxr[grank[m]];
        sbox[m] = bb;
        sarea[m] = (bb.z - bb.x + 1.0f) * (bb.w - bb.y + 1.0f);
    }
    __syncthreads();

    /* Phase B: mask build. Work unit = (column-tile c, row-block rb0),
       round-robined over 8 waves for triangle load balance. Inner loop:
       wave-uniform column window => broadcast LDS reads, conflict-free. */
    int unit = 0;
    for (int c = 0; c < W; ++c) {
        int j0 = c << 6;
        for (int rb0 = 0; rb0 < Kc && rb0 < j0 + 63; rb0 += 64, ++unit) {
            if ((unit & 7) != wv) continue;
            int r = rb0 + lane;            /* r<KMAX; rows>=Kc hit sentinels -> word=0 */
            float4 rb = sbox[r];
            float ra = sarea[r];
            u64 word = 0ull;
            #pragma unroll 8
            for (int q = 0; q < 64; ++q) {
                int cc = j0 + q;
                float4 cb = sbox[cc];
                float ih = fminf(rb.z, cb.z) - fmaxf(rb.x, cb.x) + 1.0f;
                float iw = fminf(rb.w, cb.w) - fmaxf(rb.y, cb.y) + 1.0f;
                ih = fmaxf(ih, 0.0f); iw = fmaxf(iw, 0.0f);
                /* iou>=0.5 <=> 3*inter >= ai+aj */
                bool o = (3.0f * ih * iw >= ra + sarea[cc]) && (cc > r);
                if (o) word |= (1ull << q);
            }
            maskm[r * MSTRIDE + c] = word;
        }
    }
    __syncthreads();

    /* Phase C: serial greedy scan (wave 0), chunk-8 register prefetch */
    if (t >= 64) return;
    u64 remv = 0ull;
    for (int w = 0; w < W; ++w) {
        int r0 = w << 6;
        int rend = Kc - r0; if (rend > 64) rend = 64;
        u64 curw = __shfl(remv, w);
        u64 kb = 0ull;
        for (int b0 = 0; b0 < rend; b0 += 8) {
            int n = rend - b0; if (n > 8) n = 8;
            u64 mrow[8], dg[8];
            #pragma unroll
            for (int j = 0; j < 8; ++j) {
                int rr = r0 + b0 + ((j < n) ? j : 0);
                mrow[j] = maskm[rr * MSTRIDE + lane];   /* +64 pad covers overrun */
                dg[j]   = maskm[rr * MSTRIDE + w];      /* uniform: broadcast */
            }
            #pragma unroll
            for (int j = 0; j < 8; ++j) {
                if (j < n) {
                    int b = b0 + j;
                    u64 km = ((curw >> b) & 1ull) ? 0ull : ~0ull;
                    curw |= dg[j] & km;
                    remv |= mrow[j] & km;
                    kb |= km & (1ull << b);
                }
            }
        }
        if (lane < rend)
            out[(int)grank[r0 + lane] * 6 + 5] = ((kb >> lane) & 1ull) ? 1.0f : 0.0f;
    }
}

extern "C" void kernel_launch(void* const* d_in, const int* in_sizes, int n_in,
                              void* d_out, int out_size, void* d_ws, size_t ws_size,
                              hipStream_t stream) {
    const float*  probs    = (const float*)d_in[0];
    const float4* deltas4  = (const float4*)d_in[1];
    const float4* anchors4 = (const float4*)d_in[2];
    int n_prop = in_sizes[1] / 4;   /* 522240 */
    int n_anch = in_sizes[2] / 4;   /* 65280  */
    int nfg    = n_prop * 2;        /* 1044480 */

    char* ws = (char*)d_ws;
    u32* ctr      = (u32*)(ws + CTR_OFF);
    u32* ranks    = (u32*)(ws + RANKS_OFF);
    u32* partials = (u32*)(ws + PART_OFF);
    u64* cand     = (u64*)(ws + CAND_OFF);
    float4* boxr  = (float4*)(ws + BOXR_OFF);
    u32* gbits    = (u32*)(ws + GBITS_OFF);
    float* out    = (float*)d_out;

    hist_kernel<<<NHB, 1024, 0, stream>>>((const float4*)probs, partials, n_prop);
    pivot_kernel<<<1, 1024, 0, stream>>>(partials, ctr, ranks, gbits);
    compact_kernel<<<(nfg + 255) / 256, 256, 0, stream>>>(probs, ctr, cand, nfg);
    rank_kernel<<<dim3(SLICES, 64), 256, 0, stream>>>(cand, ctr, ranks);
    decode_kernel<<<CANDMAX / 256, 256, 0, stream>>>(cand, ranks, ctr, deltas4, anchors4,
                                                     boxr, gbits, out, n_anch);
    nms_kernel<<<NGRP, 512, 0, stream>>>(gbits, boxr, out);
}

// Round 3
// 160.074 us; speedup vs baseline: 1.5560x; 1.3259x over previous
//
#include <hip/hip_runtime.h>
#include <math.h>

typedef unsigned int u32;
typedef unsigned short u16;
typedef unsigned long long u64;

#define PRE_NMS 6000
#define NBLK    94          /* ceil(6000/64) rank-bitmap words */
#define KMAX    640         /* group capacity (E[K]~375) */
#define MSTRIDE 11          /* maskm row stride, > KMAX/64 */
#define FINEB   8192        /* [0.5,1) buckets, 2^10 ulp each */
#define LOWB    8064        /* [0,0.5) buckets, bits>>17 */
#define TOTB    (FINEB + LOWB)
#define NHB     16          /* hist partial copies */
#define CANDMAX 16384
#define SLICES  8
#define NGRP    24
#define CBLK    256         /* compact blocks */
#define CBUF    512         /* compact per-block staging (E~24/block) */
#define FLOOR_BITS 0x3F000000u   /* 0.5f */

/* ws byte offsets */
#define CTR_OFF   0          /* 64 u32: [0]=cand count [1]=pivot bits */
#define RANKS_OFF 256        /* 16384 u32 -> 65792 */
#define PART_OFF  65792      /* 16 x 16256 u32 -> 1106176 */
#define CAND_OFF  1106176    /* 16384 u64 -> 1237248 */
#define BOXR_OFF  1237248    /* 6016 float4 -> 1333504 */
#define GBITS_OFF 1333504    /* 24*192 u32 -> 1351936 */

/* 1: dual-range partial histograms; full-range exact, fine resolution on top */
__global__ __launch_bounds__(1024) void hist_kernel(const float4* __restrict__ probs4,
                                                    u32* __restrict__ partials, int n_prop) {
    __shared__ u32 hf[FINEB];      /* 32 KB, 1 copy (sparse traffic) */
    __shared__ u32 hl[2][LOWB];    /* 63 KB, 2 copies (bulk traffic) */
    int t = threadIdx.x;
    for (int i = t; i < FINEB; i += 1024) hf[i] = 0u;
    for (int i = t; i < 2 * LOWB; i += 1024) ((u32*)hl)[i] = 0u;
    __syncthreads();
    u32* l = hl[(t >> 6) & 1];
    int nq = n_prop >> 2;                     /* 4 props per iter */
    int idx = blockIdx.x * 1024 + t;
    int stride = gridDim.x * 1024;
    for (int q = idx; q < nq; q += stride) {
        float4 a = probs4[3 * q + 0];
        float4 b = probs4[3 * q + 1];
        float4 c = probs4[3 * q + 2];
        float vs[8] = {a.y, a.z, b.x, b.y, b.w, c.x, c.z, c.w};
        #pragma unroll
        for (int e = 0; e < 8; ++e) {
            u32 bits = __float_as_uint(vs[e]);
            if (bits >= FLOOR_BITS) {
                u32 fb = (bits - FLOOR_BITS) >> 10; if (fb >= FINEB) fb = FINEB - 1;
                atomicAdd(&hf[fb], 1u);
            } else {
                atomicAdd(&l[bits >> 17], 1u);
            }
        }
    }
    __syncthreads();
    u32* outp = partials + blockIdx.x * TOTB;
    for (int b = t; b < FINEB; b += 1024) outp[b] = hf[b];
    for (int b = t; b < LOWB; b += 1024) outp[FINEB + b] = hl[0][b] + hl[1][b];
}

/* 2: reduce partials, suffix-scan from top -> exact pivot; zero ctr/ranks/gbits */
__global__ __launch_bounds__(1024) void pivot_kernel(const u32* __restrict__ partials,
                                                     u32* __restrict__ ctr,
                                                     u32* __restrict__ ranks,
                                                     u32* __restrict__ gbits) {
    __shared__ u32 fh[FINEB];
    __shared__ u32 sd[1024];
    int t = threadIdx.x;
    for (int i = t; i < CANDMAX; i += 1024) ranks[i] = 0u;
    for (int i = t; i < NGRP * 192; i += 1024) gbits[i] = 0u;
    if (t == 0) ctr[0] = 0u;
    for (int b = t; b < FINEB; b += 1024) {
        u32 s = 0;
        #pragma unroll
        for (int k = 0; k < NHB; ++k) s += partials[k * TOTB + b];
        fh[b] = s;
    }
    __syncthreads();
    int hi = FINEB - 1 - 8 * t;
    u32 L = 0;
    #pragma unroll
    for (int e = 0; e < 8; ++e) L += fh[hi - e];
    sd[t] = L;
    __syncthreads();
    for (int off = 1; off < 1024; off <<= 1) {
        u32 x = (t >= off) ? sd[t - off] : 0u;
        __syncthreads();
        sd[t] += x;
        __syncthreads();
    }
    u32 incl = sd[t], excl = incl - L;
    u32 fineTotal = sd[1023];
    if (excl < (u32)PRE_NMS && incl >= (u32)PRE_NMS) {
        u32 run = excl;
        #pragma unroll
        for (int e = 0; e < 8; ++e) {
            u32 c = fh[hi - e];
            if (run < (u32)PRE_NMS && run + c >= (u32)PRE_NMS)
                ctr[1] = FLOOR_BITS + ((u32)(hi - e) << 10);
            run += c;
        }
    }
    if (fineTotal >= (u32)PRE_NMS) return;

    /* fallback (never expected): continue into [0, 0.5) coarse buckets */
    u32 rem = (u32)PRE_NMS - fineTotal;
    __syncthreads();
    for (int b = t; b < FINEB; b += 1024) {
        u32 s = 0;
        if (b < LOWB) {
            #pragma unroll
            for (int k = 0; k < NHB; ++k) s += partials[k * TOTB + FINEB + b];
        }
        fh[b] = s;
    }
    __syncthreads();
    L = 0;
    #pragma unroll
    for (int e = 0; e < 8; ++e) L += fh[hi - e];
    sd[t] = L;
    __syncthreads();
    for (int off = 1; off < 1024; off <<= 1) {
        u32 x = (t >= off) ? sd[t - off] : 0u;
        __syncthreads();
        sd[t] += x;
        __syncthreads();
    }
    incl = sd[t]; excl = incl - L;
    if (excl < rem && incl >= rem) {
        u32 run = excl;
        #pragma unroll
        for (int e = 0; e < 8; ++e) {
            u32 c = fh[hi - e];
            if (run < rem && run + c >= rem)
                ctr[1] = ((u32)(hi - e)) << 17;
            run += c;
        }
    }
}

/* 3: hierarchical compaction. LDS staging + ONE global atomic per block
   (was ~5100 wave-level RMWs on a single line => ~61us of serialization).
   Same float4 quad layout as hist; key (bits<<32)|~i with i=8q+e identical
   to the old i-scan. cand order is permuted, but ranks/decode are
   order-independent (exact order recovered from keys). */
__global__ __launch_bounds__(256) void compact_kernel(const float4* __restrict__ probs4,
                                                      u32* ctr, u64* __restrict__ cand,
                                                      int n_prop) {
    __shared__ u64 sloc[CBUF];
    __shared__ u32 scnt, sbase;
    int t = threadIdx.x;
    if (t == 0) scnt = 0u;
    __syncthreads();
    u32 pivot = ctr[1];
    int nq = n_prop >> 2;
    int idx = blockIdx.x * 256 + t;
    int stride = gridDim.x * 256;
    for (int q = idx; q < nq; q += stride) {
        float4 a = probs4[3 * q + 0];
        float4 b = probs4[3 * q + 1];
        float4 c = probs4[3 * q + 2];
        float vs[8] = {a.y, a.z, b.x, b.y, b.w, c.x, c.z, c.w};
        #pragma unroll
        for (int e = 0; e < 8; ++e) {
            u32 bits = __float_as_uint(vs[e]);
            if (bits >= pivot) {
                u32 lp = atomicAdd(&scnt, 1u);      /* LDS atomic: cheap */
                u32 i = (u32)(8 * q + e);
                if (lp < (u32)CBUF) sloc[lp] = ((u64)bits << 32) | (u64)(~i);
            }
        }
    }
    __syncthreads();
    u32 cnt = scnt; if (cnt > (u32)CBUF) cnt = (u32)CBUF;
    if (t == 0) sbase = atomicAdd(&ctr[0], cnt);    /* 1 global atomic/block */
    __syncthreads();
    u32 base = sbase;
    for (u32 j = t; j < cnt; j += 256) {
        u32 pos = base + j;
        if (pos < (u32)CANDMAX) cand[pos] = sloc[j];
    }
}

/* 4: 2-D parallel rank-by-counting: grid (slice, keyblock); exact stable order */
__global__ __launch_bounds__(256) void rank_kernel(const u64* __restrict__ cand,
                                                   const u32* __restrict__ ctr,
                                                   u32* __restrict__ ranks) {
    __shared__ u64 tile[256];
    int t = threadIdx.x;
    u32 M = ctr[0]; if (M > (u32)CANDMAX) M = (u32)CANDMAX;
    int kb = blockIdx.y;
    if ((u32)(kb * 256) >= M) return;
    int i = kb * 256 + t;
    u64 key = (i < (int)M) ? cand[i] : 0ull;
    u32 Ls = (M + SLICES - 1) / SLICES;
    u32 s0 = blockIdx.x * Ls;
    u32 s1 = s0 + Ls; if (s1 > M) s1 = M;
    int cnt = 0;
    for (u32 base = s0; base < s1; base += 256) {
        u32 idx = base + t;
        tile[t] = (idx < s1) ? cand[idx] : 0ull;   /* 0-pad safe: real keys > 0 */
        __syncthreads();
        #pragma unroll 8
        for (int q = 0; q < 256; ++q) cnt += (tile[q] > key) ? 1 : 0;
        __syncthreads();
    }
    if (i < (int)M && cnt > 0) atomicAdd(&ranks[i], (u32)cnt);
}

/* 5: single-pass ROI decode + scatter. Full lane utilization, one decode per
   candidate. Writes det rows, rank-indexed box table, per-group rank bitmaps. */
__global__ __launch_bounds__(256) void decode_kernel(const u64* __restrict__ cand,
                                                     const u32* __restrict__ ranks,
                                                     const u32* __restrict__ ctr,
                                                     const float4* __restrict__ deltas4,
                                                     const float4* __restrict__ anchors4,
                                                     float4* __restrict__ boxr,
                                                     u32* __restrict__ gbits,
                                                     float* __restrict__ out,
                                                     int n_anch) {
    u32 i = blockIdx.x * 256 + threadIdx.x;
    u32 M = ctr[0]; if (M > (u32)CANDMAX) M = (u32)CANDMAX;
    if (i >= M) return;
    u32 r = ranks[i];
    if (r >= (u32)PRE_NMS) return;
    u64 key = cand[i];
    u32 bits = (u32)(key >> 32);
    u32 flat = ~((u32)key);
    int p = (int)(flat >> 1);
    int cls = (int)(flat & 1u) + 1;
    int b = p / n_anch;
    int g = b * 3 + cls;
    int aidx = p - b * n_anch;
    float score = __uint_as_float(bits);
    float4 a = anchors4[aidx];
    float4 d = deltas4[p];
    float d0 = d.x * 0.1f, d1 = d.y * 0.1f, d2 = d.z * 0.2f, d3 = d.w * 0.2f;
    float y1 = a.x * (1.0f / 512.0f), x1 = a.y * (1.0f / 512.0f);
    float y2 = a.z * (1.0f / 512.0f), x2 = a.w * (1.0f / 512.0f);
    float h = y2 - y1, w = x2 - x1;
    float cy = y1 + 0.5f * h + d0 * h;
    float cx = x1 + 0.5f * w + d1 * w;
    h = h * expf(d2);
    w = w * expf(d3);
    float ry1 = (cy - 0.5f * h) * 512.0f;
    float rx1 = (cx - 0.5f * w) * 512.0f;
    float ry2 = (cy - 0.5f * h + h) * 512.0f;
    float rx2 = (cx - 0.5f * w + w) * 512.0f;
    ry1 = fminf(fmaxf(ry1, 0.0f), 512.0f);
    rx1 = fminf(fmaxf(rx1, 0.0f), 512.0f);
    ry2 = fminf(fmaxf(ry2, 0.0f), 512.0f);
    rx2 = fminf(fmaxf(rx2, 0.0f), 512.0f);
    out[r * 6 + 0] = ry1;
    out[r * 6 + 1] = rx1;
    out[r * 6 + 2] = ry2;
    out[r * 6 + 3] = rx2;
    out[r * 6 + 4] = score;
    out[r * 6 + 5] = 1.0f;               /* default keep; nms overwrites */
    out[PRE_NMS * 6 + r] = (float)cls;
    out[PRE_NMS * 7 + r] = (float)b;
    boxr[r] = make_float4(ry1, rx1, ry2, rx2);
    atomicOr(&gbits[g * 192 + (r >> 5)], 1u << (r & 31));
}

/* 6: per-(batch,class) NMS. No re-decode: gather rank-ordered boxes from L2. */
__global__ __launch_bounds__(512) void nms_kernel(const u32* __restrict__ gbits,
                                                  const float4* __restrict__ boxr,
                                                  float* __restrict__ out) {
    __shared__ u64 maskm[KMAX * MSTRIDE + 64];   /* 56.8 KB */
    __shared__ float4 sbox[KMAX];                /* 10 KB */
    __shared__ float sarea[KMAX];
    __shared__ int bpre[96];
    __shared__ u16 grank[KMAX];                  /* pos -> rank */
    __shared__ int sK;
    int g = blockIdx.x, t = threadIdx.x, lane = t & 63, wv = t >> 6;
    const u32* rb32 = gbits + g * 192;

    /* A2: exclusive prefix over 94 bitmap words (wave 0) */
    if (t < 64) {
        u64 w0 = (u64)rb32[2 * lane] | ((u64)rb32[2 * lane + 1] << 32);
        u64 w1 = (lane < NBLK - 64)
                 ? ((u64)rb32[128 + 2 * lane] | ((u64)rb32[129 + 2 * lane] << 32)) : 0ull;
        int c0 = (int)__popcll(w0), c1 = (int)__popcll(w1);
        int i0 = c0, i1 = c1;
        #pragma unroll
        for (int off = 1; off < 64; off <<= 1) {
            int a = __shfl_up(i0, off); if (lane >= off) i0 += a;
            int b = __shfl_up(i1, off); if (lane >= off) i1 += b;
        }
        int tot0 = __shfl(i0, 63), tot1 = __shfl(i1, 63);
        bpre[lane] = i0 - c0;
        if (lane < 32) bpre[64 + lane] = tot0 + ((lane < NBLK - 64) ? (i1 - c1) : 0);
        if (lane == 0) sK = tot0 + tot1;
    }
    __syncthreads();
    int K = sK;
    if (K == 0) return;
    int Kc = (K < KMAX) ? K : KMAX;
    int W = (Kc + 63) >> 6;

    /* sentinel fill + maskm pre-zero (Phase B only writes upper-tri tiles) */
    for (int m = t; m < KMAX; m += 512) {
        sbox[m] = make_float4(-3e30f, -3e30f, -3e30f, -3e30f);
        sarea[m] = 3e38f;
    }
    for (int m = t; m < KMAX * MSTRIDE + 64; m += 512) maskm[m] = 0ull;
    __syncthreads();

    /* A3: scatter rank order -> grank */
    for (int blk = wv; blk < NBLK; blk += 8) {
        u64 wmask = (u64)rb32[2 * blk] | ((u64)rb32[2 * blk + 1] << 32);
        if ((wmask >> lane) & 1ull) {
            int pos = bpre[blk] + (int)__popcll(wmask & ((1ull << lane) - 1ull));
            if (pos < KMAX) grank[pos] = (u16)((blk << 6) | lane);
        }
    }
    __syncthreads();

    /* stage SoA in rank order from L2-hot box table (no decode) */
    for (int m = t; m < Kc; m += 512) {
        float4 bb = boxr[grank[m]];
        sbox[m] = bb;
        sarea[m] = (bb.z - bb.x + 1.0f) * (bb.w - bb.y + 1.0f);
    }
    __syncthreads();

    /* Phase B: mask build. Work unit = (column-tile c, row-block rb0),
       round-robined over 8 waves for triangle load balance. */
    int unit = 0;
    for (int c = 0; c < W; ++c) {
        int j0 = c << 6;
        for (int rb0 = 0; rb0 < Kc && rb0 < j0 + 63; rb0 += 64, ++unit) {
            if ((unit & 7) != wv) continue;
            int r = rb0 + lane;            /* r<KMAX; rows>=Kc hit sentinels -> word=0 */
            float4 rb = sbox[r];
            float ra = sarea[r];
            u64 word = 0ull;
            #pragma unroll 8
            for (int q = 0; q < 64; ++q) {
                int cc = j0 + q;
                float4 cb = sbox[cc];
                float ih = fminf(rb.z, cb.z) - fmaxf(rb.x, cb.x) + 1.0f;
                float iw = fminf(rb.w, cb.w) - fmaxf(rb.y, cb.y) + 1.0f;
                ih = fmaxf(ih, 0.0f); iw = fmaxf(iw, 0.0f);
                /* iou>=0.5 <=> 3*inter >= ai+aj */
                bool o = (3.0f * ih * iw >= ra + sarea[cc]) && (cc > r);
                if (o) word |= (1ull << q);
            }
            maskm[r * MSTRIDE + c] = word;
        }
    }
    __syncthreads();

    /* Phase C: serial greedy scan (wave 0), chunk-8 register prefetch */
    if (t >= 64) return;
    u64 remv = 0ull;
    for (int w = 0; w < W; ++w) {
        int r0 = w << 6;
        int rend = Kc - r0; if (rend > 64) rend = 64;
        u64 curw = __shfl(remv, w);
        u64 kb = 0ull;
        for (int b0 = 0; b0 < rend; b0 += 8) {
            int n = rend - b0; if (n > 8) n = 8;
            u64 mrow[8], dg[8];
            #pragma unroll
            for (int j = 0; j < 8; ++j) {
                int rr = r0 + b0 + ((j < n) ? j : 0);
                mrow[j] = maskm[rr * MSTRIDE + lane];   /* +64 pad covers overrun */
                dg[j]   = maskm[rr * MSTRIDE + w];      /* uniform: broadcast */
            }
            #pragma unroll
            for (int j = 0; j < 8; ++j) {
                if (j < n) {
                    int b = b0 + j;
                    u64 km = ((curw >> b) & 1ull) ? 0ull : ~0ull;
                    curw |= dg[j] & km;
                    remv |= mrow[j] & km;
                    kb |= km & (1ull << b);
                }
            }
        }
        if (lane < rend)
            out[(int)grank[r0 + lane] * 6 + 5] = ((kb >> lane) & 1ull) ? 1.0f : 0.0f;
    }
}

extern "C" void kernel_launch(void* const* d_in, const int* in_sizes, int n_in,
                              void* d_out, int out_size, void* d_ws, size_t ws_size,
                              hipStream_t stream) {
    const float*  probs    = (const float*)d_in[0];
    const float4* deltas4  = (const float4*)d_in[1];
    const float4* anchors4 = (const float4*)d_in[2];
    int n_prop = in_sizes[1] / 4;   /* 522240 */
    int n_anch = in_sizes[2] / 4;   /* 65280  */

    char* ws = (char*)d_ws;
    u32* ctr      = (u32*)(ws + CTR_OFF);
    u32* ranks    = (u32*)(ws + RANKS_OFF);
    u32* partials = (u32*)(ws + PART_OFF);
    u64* cand     = (u64*)(ws + CAND_OFF);
    float4* boxr  = (float4*)(ws + BOXR_OFF);
    u32* gbits    = (u32*)(ws + GBITS_OFF);
    float* out    = (float*)d_out;

    hist_kernel<<<NHB, 1024, 0, stream>>>((const float4*)probs, partials, n_prop);
    pivot_kernel<<<1, 1024, 0, stream>>>(partials, ctr, ranks, gbits);
    compact_kernel<<<CBLK, 256, 0, stream>>>((const float4*)probs, ctr, cand, n_prop);
    rank_kernel<<<dim3(SLICES, 64), 256, 0, stream>>>(cand, ctr, ranks);
    decode_kernel<<<CANDMAX / 256, 256, 0, stream>>>(cand, ranks, ctr, deltas4, anchors4,
                                                     boxr, gbits, out, n_anch);
    nms_kernel<<<NGRP, 512, 0, stream>>>(gbits, boxr, out);
}

// Round 4
// 153.465 us; speedup vs baseline: 1.6230x; 1.0431x over previous
//
#include <hip/hip_runtime.h>
#include <math.h>

typedef unsigned int u32;
typedef unsigned short u16;
typedef unsigned long long u64;

#define PRE_NMS 6000
#define NBLK    94          /* ceil(6000/64) rank-bitmap words */
#define KMAX    640         /* group capacity (E[K]~375) */
#define MSTRIDE 11          /* mask row stride, > KMAX/64 */
#define MAXW    10          /* max 64-blocks per group (KMAX/64) */
#define MTILE   (MAXW * MAXW)
#define FINEB   8192        /* [0.5,1) buckets, 2^10 ulp each */
#define LOWB    8064        /* [0,0.5) buckets, bits>>17 */
#define TOTB    (FINEB + LOWB)
#define NHB     16          /* hist partial copies */
#define CANDMAX 16384
#define SLICES  8
#define NGRP    24
#define CBLK    256         /* compact blocks */
#define CBUF    512         /* compact per-block staging (E~24/block) */
#define FLOOR_BITS 0x3F000000u   /* 0.5f */

/* ws byte offsets */
#define CTR_OFF    0          /* 64 u32: [0]=cand count [1]=pivot bits */
#define RANKS_OFF  256        /* 16384 u32 -> 65792 */
#define PART_OFF   65792      /* 16 x 16256 u32 -> 1106176 */
#define CAND_OFF   1106176    /* 16384 u64 -> 1237248 */
#define BOXR_OFF   1237248    /* 6016 float4 -> 1333504 */
#define GBITS_OFF  1333504    /* 24*192 u32 -> 1351936 */
#define KG_OFF     1351936    /* 64 u32 -> 1352192 */
#define GRANKG_OFF 1352192    /* 24*640 u32 -> 1413632 */
#define BOXG_OFF   1413632    /* 24*640 float4 -> 1659392 */
#define AREAG_OFF  1659392    /* 24*640 f32 -> 1720832 */
#define MASKG_OFF  1720832    /* 24*640*11 u64 -> 3072512 */

/* 1: dual-range partial histograms; full-range exact, fine resolution on top */
__global__ __launch_bounds__(1024) void hist_kernel(const float4* __restrict__ probs4,
                                                    u32* __restrict__ partials, int n_prop) {
    __shared__ u32 hf[FINEB];      /* 32 KB, 1 copy (sparse traffic) */
    __shared__ u32 hl[2][LOWB];    /* 63 KB, 2 copies (bulk traffic) */
    int t = threadIdx.x;
    for (int i = t; i < FINEB; i += 1024) hf[i] = 0u;
    for (int i = t; i < 2 * LOWB; i += 1024) ((u32*)hl)[i] = 0u;
    __syncthreads();
    u32* l = hl[(t >> 6) & 1];
    int nq = n_prop >> 2;                     /* 4 props per iter */
    int idx = blockIdx.x * 1024 + t;
    int stride = gridDim.x * 1024;
    for (int q = idx; q < nq; q += stride) {
        float4 a = probs4[3 * q + 0];
        float4 b = probs4[3 * q + 1];
        float4 c = probs4[3 * q + 2];
        float vs[8] = {a.y, a.z, b.x, b.y, b.w, c.x, c.z, c.w};
        #pragma unroll
        for (int e = 0; e < 8; ++e) {
            u32 bits = __float_as_uint(vs[e]);
            if (bits >= FLOOR_BITS) {
                u32 fb = (bits - FLOOR_BITS) >> 10; if (fb >= FINEB) fb = FINEB - 1;
                atomicAdd(&hf[fb], 1u);
            } else {
                atomicAdd(&l[bits >> 17], 1u);
            }
        }
    }
    __syncthreads();
    u32* outp = partials + blockIdx.x * TOTB;
    for (int b = t; b < FINEB; b += 1024) outp[b] = hf[b];
    for (int b = t; b < LOWB; b += 1024) outp[FINEB + b] = hl[0][b] + hl[1][b];
}

/* 2: reduce partials, suffix-scan from top -> exact pivot; zero ctr/ranks/gbits */
__global__ __launch_bounds__(1024) void pivot_kernel(const u32* __restrict__ partials,
                                                     u32* __restrict__ ctr,
                                                     u32* __restrict__ ranks,
                                                     u32* __restrict__ gbits) {
    __shared__ u32 fh[FINEB];
    __shared__ u32 sd[1024];
    int t = threadIdx.x;
    for (int i = t; i < CANDMAX; i += 1024) ranks[i] = 0u;
    for (int i = t; i < NGRP * 192; i += 1024) gbits[i] = 0u;
    if (t == 0) ctr[0] = 0u;
    for (int b = t; b < FINEB; b += 1024) {
        u32 s = 0;
        #pragma unroll
        for (int k = 0; k < NHB; ++k) s += partials[k * TOTB + b];
        fh[b] = s;
    }
    __syncthreads();
    int hi = FINEB - 1 - 8 * t;
    u32 L = 0;
    #pragma unroll
    for (int e = 0; e < 8; ++e) L += fh[hi - e];
    sd[t] = L;
    __syncthreads();
    for (int off = 1; off < 1024; off <<= 1) {
        u32 x = (t >= off) ? sd[t - off] : 0u;
        __syncthreads();
        sd[t] += x;
        __syncthreads();
    }
    u32 incl = sd[t], excl = incl - L;
    u32 fineTotal = sd[1023];
    if (excl < (u32)PRE_NMS && incl >= (u32)PRE_NMS) {
        u32 run = excl;
        #pragma unroll
        for (int e = 0; e < 8; ++e) {
            u32 c = fh[hi - e];
            if (run < (u32)PRE_NMS && run + c >= (u32)PRE_NMS)
                ctr[1] = FLOOR_BITS + ((u32)(hi - e) << 10);
            run += c;
        }
    }
    if (fineTotal >= (u32)PRE_NMS) return;

    /* fallback (never expected): continue into [0, 0.5) coarse buckets */
    u32 rem = (u32)PRE_NMS - fineTotal;
    __syncthreads();
    for (int b = t; b < FINEB; b += 1024) {
        u32 s = 0;
        if (b < LOWB) {
            #pragma unroll
            for (int k = 0; k < NHB; ++k) s += partials[k * TOTB + FINEB + b];
        }
        fh[b] = s;
    }
    __syncthreads();
    L = 0;
    #pragma unroll
    for (int e = 0; e < 8; ++e) L += fh[hi - e];
    sd[t] = L;
    __syncthreads();
    for (int off = 1; off < 1024; off <<= 1) {
        u32 x = (t >= off) ? sd[t - off] : 0u;
        __syncthreads();
        sd[t] += x;
        __syncthreads();
    }
    incl = sd[t]; excl = incl - L;
    if (excl < rem && incl >= rem) {
        u32 run = excl;
        #pragma unroll
        for (int e = 0; e < 8; ++e) {
            u32 c = fh[hi - e];
            if (run < rem && run + c >= rem)
                ctr[1] = ((u32)(hi - e)) << 17;
            run += c;
        }
    }
}

/* 3: hierarchical compaction. LDS staging + ONE global atomic per block. */
__global__ __launch_bounds__(256) void compact_kernel(const float4* __restrict__ probs4,
                                                      u32* ctr, u64* __restrict__ cand,
                                                      int n_prop) {
    __shared__ u64 sloc[CBUF];
    __shared__ u32 scnt, sbase;
    int t = threadIdx.x;
    if (t == 0) scnt = 0u;
    __syncthreads();
    u32 pivot = ctr[1];
    int nq = n_prop >> 2;
    int idx = blockIdx.x * 256 + t;
    int stride = gridDim.x * 256;
    for (int q = idx; q < nq; q += stride) {
        float4 a = probs4[3 * q + 0];
        float4 b = probs4[3 * q + 1];
        float4 c = probs4[3 * q + 2];
        float vs[8] = {a.y, a.z, b.x, b.y, b.w, c.x, c.z, c.w};
        #pragma unroll
        for (int e = 0; e < 8; ++e) {
            u32 bits = __float_as_uint(vs[e]);
            if (bits >= pivot) {
                u32 lp = atomicAdd(&scnt, 1u);      /* LDS atomic: cheap */
                u32 i = (u32)(8 * q + e);
                if (lp < (u32)CBUF) sloc[lp] = ((u64)bits << 32) | (u64)(~i);
            }
        }
    }
    __syncthreads();
    u32 cnt = scnt; if (cnt > (u32)CBUF) cnt = (u32)CBUF;
    if (t == 0) sbase = atomicAdd(&ctr[0], cnt);    /* 1 global atomic/block */
    __syncthreads();
    u32 base = sbase;
    for (u32 j = t; j < cnt; j += 256) {
        u32 pos = base + j;
        if (pos < (u32)CANDMAX) cand[pos] = sloc[j];
    }
}

/* 4: 2-D parallel rank-by-counting: grid (slice, keyblock); exact stable order */
__global__ __launch_bounds__(256) void rank_kernel(const u64* __restrict__ cand,
                                                   const u32* __restrict__ ctr,
                                                   u32* __restrict__ ranks) {
    __shared__ u64 tile[256];
    int t = threadIdx.x;
    u32 M = ctr[0]; if (M > (u32)CANDMAX) M = (u32)CANDMAX;
    int kb = blockIdx.y;
    if ((u32)(kb * 256) >= M) return;
    int i = kb * 256 + t;
    u64 key = (i < (int)M) ? cand[i] : 0ull;
    u32 Ls = (M + SLICES - 1) / SLICES;
    u32 s0 = blockIdx.x * Ls;
    u32 s1 = s0 + Ls; if (s1 > M) s1 = M;
    int cnt = 0;
    for (u32 base = s0; base < s1; base += 256) {
        u32 idx = base + t;
        tile[t] = (idx < s1) ? cand[idx] : 0ull;   /* 0-pad safe: real keys > 0 */
        __syncthreads();
        #pragma unroll 8
        for (int q = 0; q < 256; ++q) cnt += (tile[q] > key) ? 1 : 0;
        __syncthreads();
    }
    if (i < (int)M && cnt > 0) atomicAdd(&ranks[i], (u32)cnt);
}

/* 5: single-pass ROI decode + scatter. Writes det rows, rank-indexed box
   table, per-group rank bitmaps. */
__global__ __launch_bounds__(256) void decode_kernel(const u64* __restrict__ cand,
                                                     const u32* __restrict__ ranks,
                                                     const u32* __restrict__ ctr,
                                                     const float4* __restrict__ deltas4,
                                                     const float4* __restrict__ anchors4,
                                                     float4* __restrict__ boxr,
                                                     u32* __restrict__ gbits,
                                                     float* __restrict__ out,
                                                     int n_anch) {
    u32 i = blockIdx.x * 256 + threadIdx.x;
    u32 M = ctr[0]; if (M > (u32)CANDMAX) M = (u32)CANDMAX;
    if (i >= M) return;
    u32 r = ranks[i];
    if (r >= (u32)PRE_NMS) return;
    u64 key = cand[i];
    u32 bits = (u32)(key >> 32);
    u32 flat = ~((u32)key);
    int p = (int)(flat >> 1);
    int cls = (int)(flat & 1u) + 1;
    int b = p / n_anch;
    int g = b * 3 + cls;
    int aidx = p - b * n_anch;
    float score = __uint_as_float(bits);
    float4 a = anchors4[aidx];
    float4 d = deltas4[p];
    float d0 = d.x * 0.1f, d1 = d.y * 0.1f, d2 = d.z * 0.2f, d3 = d.w * 0.2f;
    float y1 = a.x * (1.0f / 512.0f), x1 = a.y * (1.0f / 512.0f);
    float y2 = a.z * (1.0f / 512.0f), x2 = a.w * (1.0f / 512.0f);
    float h = y2 - y1, w = x2 - x1;
    float cy = y1 + 0.5f * h + d0 * h;
    float cx = x1 + 0.5f * w + d1 * w;
    h = h * expf(d2);
    w = w * expf(d3);
    float ry1 = (cy - 0.5f * h) * 512.0f;
    float rx1 = (cx - 0.5f * w) * 512.0f;
    float ry2 = (cy - 0.5f * h + h) * 512.0f;
    float rx2 = (cx - 0.5f * w + w) * 512.0f;
    ry1 = fminf(fmaxf(ry1, 0.0f), 512.0f);
    rx1 = fminf(fmaxf(rx1, 0.0f), 512.0f);
    ry2 = fminf(fmaxf(ry2, 0.0f), 512.0f);
    rx2 = fminf(fmaxf(rx2, 0.0f), 512.0f);
    out[r * 6 + 0] = ry1;
    out[r * 6 + 1] = rx1;
    out[r * 6 + 2] = ry2;
    out[r * 6 + 3] = rx2;
    out[r * 6 + 4] = score;
    out[r * 6 + 5] = 1.0f;               /* default keep; greedy overwrites */
    out[PRE_NMS * 6 + r] = (float)cls;
    out[PRE_NMS * 7 + r] = (float)b;
    boxr[r] = make_float4(ry1, rx1, ry2, rx2);
    atomicOr(&gbits[g * 192 + (r >> 5)], 1u << (r & 31));
}

/* 6: per-group prep: prefix bitmap -> rank-ordered box table in global
   (sentinel-padded to KMAX), grank table, K. */
__global__ __launch_bounds__(512) void prep_kernel(const u32* __restrict__ gbits,
                                                   const float4* __restrict__ boxr,
                                                   u32* __restrict__ kg,
                                                   u32* __restrict__ grankg,
                                                   float4* __restrict__ boxg,
                                                   float* __restrict__ areag) {
    __shared__ int bpre[96];
    __shared__ u16 grankS[KMAX];
    __shared__ int sK;
    int g = blockIdx.x, t = threadIdx.x, lane = t & 63, wv = t >> 6;
    const u32* rb32 = gbits + g * 192;

    if (t < 64) {
        u64 w0 = (u64)rb32[2 * lane] | ((u64)rb32[2 * lane + 1] << 32);
        u64 w1 = (lane < NBLK - 64)
                 ? ((u64)rb32[128 + 2 * lane] | ((u64)rb32[129 + 2 * lane] << 32)) : 0ull;
        int c0 = (int)__popcll(w0), c1 = (int)__popcll(w1);
        int i0 = c0, i1 = c1;
        #pragma unroll
        for (int off = 1; off < 64; off <<= 1) {
            int a = __shfl_up(i0, off); if (lane >= off) i0 += a;
            int b = __shfl_up(i1, off); if (lane >= off) i1 += b;
        }
        int tot0 = __shfl(i0, 63), tot1 = __shfl(i1, 63);
        bpre[lane] = i0 - c0;
        if (lane < 32) bpre[64 + lane] = tot0 + ((lane < NBLK - 64) ? (i1 - c1) : 0);
        if (lane == 0) { sK = tot0 + tot1; kg[g] = (u32)(tot0 + tot1); }
    }
    __syncthreads();
    int K = sK;
    if (K == 0) return;
    int Kc = (K < KMAX) ? K : KMAX;

    for (int blk = wv; blk < NBLK; blk += 8) {
        u64 wmask = (u64)rb32[2 * blk] | ((u64)rb32[2 * blk + 1] << 32);
        if ((wmask >> lane) & 1ull) {
            int pos = bpre[blk] + (int)__popcll(wmask & ((1ull << lane) - 1ull));
            if (pos < KMAX) grankS[pos] = (u16)((blk << 6) | lane);
        }
    }
    __syncthreads();

    float4* bg = boxg + g * KMAX;
    float*  ag = areag + g * KMAX;
    u32*    gr = grankg + g * KMAX;
    for (int m = t; m < KMAX; m += 512) {
        if (m < Kc) {
            int r = grankS[m];
            float4 bb = boxr[r];
            bg[m] = bb;
            ag[m] = (bb.z - bb.x + 1.0f) * (bb.w - bb.y + 1.0f);
            gr[m] = (u32)r;
        } else {
            bg[m] = make_float4(-3e30f, -3e30f, -3e30f, -3e30f);
            ag[m] = 3e38f;
        }
    }
}

/* 7: register-resident 64x64 IoU tiles, one 1-wave block per (group, tile).
   Lane holds its row box AND its column box; column broadcast via shuffle.
   Sub-diagonal tiles write zeros (replaces old LDS pre-zero). */
__global__ __launch_bounds__(64) void mask_kernel(const u32* __restrict__ kg,
                                                  const float4* __restrict__ boxg,
                                                  const float* __restrict__ areag,
                                                  u64* __restrict__ maskg) {
    int g = blockIdx.y;
    u32 K = kg[g];
    if (K == 0u) return;
    int Kc = (K < (u32)KMAX) ? (int)K : KMAX;
    int W = (Kc + 63) >> 6;
    int u = blockIdx.x;
    int c = u / MAXW, rbk = u % MAXW;
    if (c >= W || rbk >= W) return;
    int lane = threadIdx.x;
    int r = rbk * 64 + lane;
    u64* mg = maskg + (size_t)g * (KMAX * MSTRIDE);
    if (rbk > c) { mg[r * MSTRIDE + c] = 0ull; return; }
    int j0 = c << 6;
    const float4* bg = boxg + g * KMAX;
    const float*  ag = areag + g * KMAX;
    float4 rb = bg[r];
    float  ra = ag[r];
    float4 cb = bg[j0 + lane];
    float  ca = ag[j0 + lane];
    u64 word = 0ull;
    #pragma unroll 8
    for (int q = 0; q < 64; ++q) {
        float cbx = __shfl(cb.x, q);
        float cby = __shfl(cb.y, q);
        float cbz = __shfl(cb.z, q);
        float cbw = __shfl(cb.w, q);
        float cav = __shfl(ca, q);
        float ih = fminf(rb.z, cbz) - fmaxf(rb.x, cbx) + 1.0f;
        float iw = fminf(rb.w, cbw) - fmaxf(rb.y, cby) + 1.0f;
        ih = fmaxf(ih, 0.0f); iw = fmaxf(iw, 0.0f);
        /* iou>=0.5 <=> 3*inter >= ai+aj */
        bool o = (3.0f * ih * iw >= ra + cav) && ((j0 + q) > r);
        if (o) word |= (1ull << q);
    }
    mg[r * MSTRIDE + c] = word;
}

/* 8: per-group serial greedy. Stage the 33KB mask L3->LDS coalesced, then
   identical chunk-8 prefetch scan as before. */
__global__ __launch_bounds__(512) void greedy_kernel(const u32* __restrict__ kg,
                                                     const u32* __restrict__ grankg,
                                                     const u64* __restrict__ maskg,
                                                     float* __restrict__ out) {
    __shared__ u64 maskm[KMAX * MSTRIDE + 64];   /* 56.8 KB */
    __shared__ u16 grank[KMAX];
    int g = blockIdx.x, t = threadIdx.x, lane = t & 63;
    u32 K = kg[g];
    if (K == 0u) return;
    int Kc = (K < (u32)KMAX) ? (int)K : KMAX;
    int W = (Kc + 63) >> 6;
    const u64* mg = maskg + (size_t)g * (KMAX * MSTRIDE);
    int nw = Kc * MSTRIDE;
    for (int m = t; m < nw; m += 512) maskm[m] = mg[m];
    for (int m = nw + t; m < nw + 64; m += 512) maskm[m] = 0ull;
    for (int m = t; m < Kc; m += 512) grank[m] = (u16)grankg[g * KMAX + m];
    __syncthreads();

    if (t >= 64) return;
    u64 remv = 0ull;
    for (int w = 0; w < W; ++w) {
        int r0 = w << 6;
        int rend = Kc - r0; if (rend > 64) rend = 64;
        u64 curw = __shfl(remv, w);
        u64 kb = 0ull;
        for (int b0 = 0; b0 < rend; b0 += 8) {
            int n = rend - b0; if (n > 8) n = 8;
            u64 mrow[8], dg[8];
            #pragma unroll
            for (int j = 0; j < 8; ++j) {
                int rr = r0 + b0 + ((j < n) ? j : 0);
                mrow[j] = maskm[rr * MSTRIDE + lane];   /* +64 pad covers overrun */
                dg[j]   = maskm[rr * MSTRIDE + w];      /* uniform: broadcast */
            }
            #pragma unroll
            for (int j = 0; j < 8; ++j) {
                if (j < n) {
                    int b = b0 + j;
                    u64 km = ((curw >> b) & 1ull) ? 0ull : ~0ull;
                    curw |= dg[j] & km;
                    remv |= mrow[j] & km;
                    kb |= km & (1ull << b);
                }
            }
        }
        if (lane < rend)
            out[(int)grank[r0 + lane] * 6 + 5] = ((kb >> lane) & 1ull) ? 1.0f : 0.0f;
    }
}

extern "C" void kernel_launch(void* const* d_in, const int* in_sizes, int n_in,
                              void* d_out, int out_size, void* d_ws, size_t ws_size,
                              hipStream_t stream) {
    const float*  probs    = (const float*)d_in[0];
    const float4* deltas4  = (const float4*)d_in[1];
    const float4* anchors4 = (const float4*)d_in[2];
    int n_prop = in_sizes[1] / 4;   /* 522240 */
    int n_anch = in_sizes[2] / 4;   /* 65280  */

    char* ws = (char*)d_ws;
    u32* ctr      = (u32*)(ws + CTR_OFF);
    u32* ranks    = (u32*)(ws + RANKS_OFF);
    u32* partials = (u32*)(ws + PART_OFF);
    u64* cand     = (u64*)(ws + CAND_OFF);
    float4* boxr  = (float4*)(ws + BOXR_OFF);
    u32* gbits    = (u32*)(ws + GBITS_OFF);
    u32* kg       = (u32*)(ws + KG_OFF);
    u32* grankg   = (u32*)(ws + GRANKG_OFF);
    float4* boxg  = (float4*)(ws + BOXG_OFF);
    float* areag  = (float*)(ws + AREAG_OFF);
    u64* maskg    = (u64*)(ws + MASKG_OFF);
    float* out    = (float*)d_out;

    hist_kernel<<<NHB, 1024, 0, stream>>>((const float4*)probs, partials, n_prop);
    pivot_kernel<<<1, 1024, 0, stream>>>(partials, ctr, ranks, gbits);
    compact_kernel<<<CBLK, 256, 0, stream>>>((const float4*)probs, ctr, cand, n_prop);
    rank_kernel<<<dim3(SLICES, 64), 256, 0, stream>>>(cand, ctr, ranks);
    decode_kernel<<<CANDMAX / 256, 256, 0, stream>>>(cand, ranks, ctr, deltas4, anchors4,
                                                     boxr, gbits, out, n_anch);
    prep_kernel<<<NGRP, 512, 0, stream>>>(gbits, boxr, kg, grankg, boxg, areag);
    mask_kernel<<<dim3(MTILE, NGRP), 64, 0, stream>>>(kg, boxg, areag, maskg);
    greedy_kernel<<<NGRP, 512, 0, stream>>>(kg, grankg, maskg, out);
}